// Round 1
// baseline (799.505 us; speedup 1.0000x reference)
//
#include <hip/hip_runtime.h>
#include <cstddef>

#define BB 128
#define DD 100

// W2^T staged once by k_fwd: d_w2t[j*DD + o] = W2[o*DD + j].
// Static __device__ buffer: no hipMalloc, graph-capture safe.
__device__ float d_w2t[DD * DD];

// ---------------------------------------------------------------------------
// Kernel 1: per-sample forward. z = x@W1^T + b1 ; h = gelu(z) ;
// out = h@W2^T + b2. Also writes g1 = gelu'(z), g2 = gelu''(z).
// Blocks i<100 additionally transpose one row of W2 into d_w2t (consumed by
// k_jac/k_hess, which follow on the same stream).
// ---------------------------------------------------------------------------
__global__ __launch_bounds__(128) void k_fwd(
    const float* __restrict__ x, const float* __restrict__ W1,
    const float* __restrict__ b1, const float* __restrict__ W2,
    const float* __restrict__ b2, float* __restrict__ out,
    float* __restrict__ g1, float* __restrict__ g2)
{
    const int i = blockIdx.x;
    const int t = threadIdx.x;
    __shared__ float xs[DD];
    __shared__ float hs[DD];
    if (t < DD) {
        xs[t] = x[i * DD + t];
        if (i < DD) d_w2t[i * DD + t] = W2[t * DD + i];  // w2t[i][t] = W2[t][i]
    }
    __syncthreads();
    if (t < DD) {
        float z = b1[t];
        const float* w = W1 + t * DD;
        for (int k = 0; k < DD; ++k) z = fmaf(xs[k], w[k], z);
        const float cdf = 0.5f * (1.0f + erff(z * 0.7071067811865476f));
        const float pdf = 0.3989422804014327f * expf(-0.5f * z * z);
        hs[t] = z * cdf;                       // gelu(z)
        g1[i * DD + t] = cdf + z * pdf;        // gelu'(z)
        g2[i * DD + t] = (2.0f - z * z) * pdf; // gelu''(z)
    }
    __syncthreads();
    if (t < DD) {
        float acc = b2[t];
        const float* w = W2 + t * DD;
        for (int j = 0; j < DD; ++j) acc = fmaf(hs[j], w[j], acc);
        out[i * DD + t] = acc;
    }
}

// ---------------------------------------------------------------------------
// Kernel 2: Jacobian. jac[i,o,l] = sum_j W2[o,j]*g1[i,j]*W1[j,l].
// LDS holds At[j][o] = W2[o,j]*g1[i,j] (j-major => per-j operand reads are
// contiguous float2s with immediate offsets). W1 rows stream from L1.
// 250 threads: 10(o) x 4(l) register tile, K=100.
// ---------------------------------------------------------------------------
__global__ __launch_bounds__(256) void k_jac(
    const float* __restrict__ W1, const float* __restrict__ g1,
    float* __restrict__ jac)
{
    const int i = blockIdx.x;
    const int t = threadIdx.x;
    __shared__ float At[DD * DD];   // At[j*DD + o]
    __shared__ float gs[DD];
    if (t < DD) gs[t] = g1[i * DD + t];
    __syncthreads();
    // Coalesced float4 staging: 100-float rows = 25 float4s, never split.
    {
        const float4* w4 = (const float4*)d_w2t;
        float4* A4 = (float4*)At;
        for (int q = t; q < DD * DD / 4; q += 256) {
            const float s = gs[q / 25];        // j = q/25
            const float4 v = w4[q];
            A4[q] = make_float4(v.x * s, v.y * s, v.z * s, v.w * s);
        }
    }
    __syncthreads();
    if (t < 250) {
        const int l0 = (t % 25) * 4;
        const int o0 = (t / 25) * 10;          // even -> float2-aligned
        float acc[10][4];
#pragma unroll
        for (int o = 0; o < 10; ++o)
#pragma unroll
            for (int c = 0; c < 4; ++c) acc[o][c] = 0.0f;
        const float* wrow = W1 + l0;
#pragma unroll 10
        for (int j = 0; j < DD; ++j) {
            const float4 w = *(const float4*)(wrow + j * DD);
            const float2* u = (const float2*)(At + j * DD + o0);
            const float2 a0 = u[0], a1 = u[1], a2 = u[2], a3 = u[3], a4 = u[4];
            const float a[10] = {a0.x, a0.y, a1.x, a1.y, a2.x,
                                 a2.y, a3.x, a3.y, a4.x, a4.y};
#pragma unroll
            for (int o = 0; o < 10; ++o) {
                acc[o][0] = fmaf(a[o], w.x, acc[o][0]);
                acc[o][1] = fmaf(a[o], w.y, acc[o][1]);
                acc[o][2] = fmaf(a[o], w.z, acc[o][2]);
                acc[o][3] = fmaf(a[o], w.w, acc[o][3]);
            }
        }
#pragma unroll
        for (int o = 0; o < 10; ++o)
            *(float4*)(jac + ((size_t)i * DD + o0 + o) * DD + l0) =
                make_float4(acc[o][0], acc[o][1], acc[o][2], acc[o][3]);
    }
}

// ---------------------------------------------------------------------------
// Kernel 3: Hessian. hess[i,o,k,l] = sum_j W2[o,j]*g2[i,j]*W1[j,k]*W1[j,l].
// One block per (i,k). LDS holds Ut[j][o] = W2[o,j]*g2[i,j]*W1[j,k]
// (j-major). Inner loop per j: 1 global_load_dwordx4 (W1 row slice) +
// 5 ds_read_b64 (immediate offsets, broadcast across 25-lane groups) +
// 40 FMA. #pragma unroll 10 folds all offsets into immediates.
// ---------------------------------------------------------------------------
__global__ __launch_bounds__(256) void k_hess(
    const float* __restrict__ W1, const float* __restrict__ g2,
    float* __restrict__ hess)
{
    const int k = blockIdx.x;
    const int i = blockIdx.y;
    const int t = threadIdx.x;
    __shared__ float Ut[DD * DD];   // Ut[j*DD + o]
    __shared__ float sj[DD];
    if (t < DD) sj[t] = g2[i * DD + t] * W1[t * DD + k];
    __syncthreads();
    {
        const float4* w4 = (const float4*)d_w2t;
        float4* U4 = (float4*)Ut;
        for (int q = t; q < DD * DD / 4; q += 256) {
            const float s = sj[q / 25];        // j = q/25
            const float4 v = w4[q];
            U4[q] = make_float4(v.x * s, v.y * s, v.z * s, v.w * s);
        }
    }
    __syncthreads();
    if (t < 250) {
        const int l0 = (t % 25) * 4;
        const int o0 = (t / 25) * 10;          // even -> float2-aligned
        float acc[10][4];
#pragma unroll
        for (int o = 0; o < 10; ++o)
#pragma unroll
            for (int c = 0; c < 4; ++c) acc[o][c] = 0.0f;
        const float* wrow = W1 + l0;
#pragma unroll 10
        for (int j = 0; j < DD; ++j) {
            const float4 w = *(const float4*)(wrow + j * DD);
            const float2* u = (const float2*)(Ut + j * DD + o0);
            const float2 a0 = u[0], a1 = u[1], a2 = u[2], a3 = u[3], a4 = u[4];
            const float a[10] = {a0.x, a0.y, a1.x, a1.y, a2.x,
                                 a2.y, a3.x, a3.y, a4.x, a4.y};
#pragma unroll
            for (int o = 0; o < 10; ++o) {
                acc[o][0] = fmaf(a[o], w.x, acc[o][0]);
                acc[o][1] = fmaf(a[o], w.y, acc[o][1]);
                acc[o][2] = fmaf(a[o], w.z, acc[o][2]);
                acc[o][3] = fmaf(a[o], w.w, acc[o][3]);
            }
        }
#pragma unroll
        for (int o = 0; o < 10; ++o) {
            const size_t off = (((size_t)i * DD + o0 + o) * DD + k) * DD + l0;
            *(float4*)(hess + off) =
                make_float4(acc[o][0], acc[o][1], acc[o][2], acc[o][3]);
        }
    }
}

extern "C" void kernel_launch(void* const* d_in, const int* in_sizes, int n_in,
                              void* d_out, int out_size, void* d_ws, size_t ws_size,
                              hipStream_t stream)
{
    const float* x  = (const float*)d_in[0];
    const float* W1 = (const float*)d_in[1];
    const float* b1 = (const float*)d_in[2];
    const float* W2 = (const float*)d_in[3];
    const float* b2 = (const float*)d_in[4];

    float* out  = (float*)d_out;                       // (128,100)
    float* jac  = out + (size_t)BB * DD;               // (128,100,100)
    float* hess = jac + (size_t)BB * DD * DD;          // (128,100,100,100)

    float* g1 = (float*)d_ws;                          // (128,100)
    float* g2 = g1 + (size_t)BB * DD;                  // (128,100)

    k_fwd<<<BB, 128, 0, stream>>>(x, W1, b1, W2, b2, out, g1, g2);
    k_jac<<<BB, 256, 0, stream>>>(W1, g1, jac);
    k_hess<<<dim3(DD, BB), 256, 0, stream>>>(W1, g2, hess);
}